// Round 10
// baseline (123.670 us; speedup 1.0000x reference)
//
#include <hip/hip_runtime.h>

typedef unsigned short u16;
typedef unsigned int u32;
typedef unsigned long long uptr;
typedef __attribute__((ext_vector_type(8))) short short8;
typedef __attribute__((ext_vector_type(4))) float f32x4;
typedef __attribute__((ext_vector_type(16))) float f32x16;
typedef __attribute__((ext_vector_type(4))) u32 u32x4;

#define LOG2E 1.4426950408889634f
#define RSQRT_MD 0.04419417382415922f

__device__ __forceinline__ u16 f2bf(float f) {
  u32 u = __builtin_bit_cast(u32, f);
  u32 r = u + 0x7fffu + ((u >> 16) & 1u);
  return (u16)(r >> 16);
}

__device__ __forceinline__ uint4 pack8(float4 a, float4 b) {
  uint4 c;
  c.x = (u32)f2bf(a.x) | ((u32)f2bf(a.y) << 16);
  c.y = (u32)f2bf(a.z) | ((u32)f2bf(a.w) << 16);
  c.z = (u32)f2bf(b.x) | ((u32)f2bf(b.y) << 16);
  c.w = (u32)f2bf(b.z) | ((u32)f2bf(b.w) << 16);
  return c;
}

// v_cvt_pk_bf16_f32: packs (a -> low bf16, b -> high bf16), RNE
__device__ __forceinline__ u32 cvtpk_bf16(float a, float b) {
  u32 r;
  asm("v_cvt_pk_bf16_f32 %0, %1, %2" : "=v"(r) : "v"(a), "v"(b));
  return r;
}

// v_permlane32_swap_b32: a' = [a.lo|b.lo], b' = [a.hi|b.hi]
__device__ __forceinline__ void pl32swap(u32& a, u32& b) {
  asm volatile("v_permlane32_swap_b32 %0, %1" : "+v"(a), "+v"(b));
}

// LDS tile: rows of 64 bf16 = 8 chunks of 16B, chunk XOR-swizzled by row&7
__device__ __forceinline__ int swo(int row, int chunk) {
  return row * 64 + ((chunk ^ (row & 7)) * 8);
}

// async global->LDS, 16B per lane; LDS dest = wave-uniform base + lane*16
__device__ __forceinline__ void gl_lds16(const u16* g, u16* l) {
  auto gp = (const __attribute__((address_space(1))) u16*)(uptr)g;
  auto lp = (__attribute__((address_space(3))) u16*)(uptr)l;
  __builtin_amdgcn_global_load_lds(gp, lp, 16, 0, 0);
}

// ---------------- Kernel 1: weight prep ----------------
// wf[nt_g(12)][kt(8)][kc(2)][lane(64)][8] bf16 fragment-contiguous QKV weights;
// wot[512][64] bf16 WoSum^T. (unchanged)
__global__ __launch_bounds__(256) void prep(
    const float* __restrict__ Wq, const float* __restrict__ Wk,
    const float* __restrict__ Wv, const float* __restrict__ Wo,
    u16* __restrict__ wf, u16* __restrict__ wot) {
  int idx = blockIdx.x * 256 + threadIdx.x;
  if (idx < 3 * 64 * 512) {
    int row = idx >> 9, k = idx & 511;
    int mat = row >> 6, n = row & 63;
    const float* W = (mat == 0) ? Wq : ((mat == 1) ? Wk : Wv);
    float scale = (mat == 0) ? (LOG2E * RSQRT_MD) : 1.0f;
    u16 v = f2bf(W[k * 64 + n] * scale);
    int nt_g = row >> 4, ml = row & 15;
    int kt = k >> 6, kc = (k >> 5) & 1, quad = (k >> 3) & 3, j = k & 7;
    wf[((((nt_g * 8 + kt) * 2 + kc) * 64) + quad * 16 + ml) * 8 + j] = v;
  } else {
    int j = idx - 3 * 64 * 512;
    int d = j >> 6, e = j & 63;
    float s = 0.f;
#pragma unroll
    for (int h = 0; h < 8; ++h) s += Wo[(size_t)(h * 64 + e) * 512 + d];
    wot[j] = f2bf(s);
  }
}

// ---------------- Kernel 2: QKV projection ----------------
// 16-row tiles, grid 1024 -> 4 blocks/CU x 4 waves = 16 waves/CU = 4/SIMD
// (was 2/SIMD at grid 512). Per-wave structure = proven R4 code with the
// sub dimension dropped; same wf-table B loads, same epilogue layouts.
__global__ __launch_bounds__(256) void qkv_proj(
    const float* __restrict__ x, const u16* __restrict__ wf,
    u16* __restrict__ Q, u16* __restrict__ K, u16* __restrict__ V) {
  __shared__ __align__(16) u16 xt[16 * 512];  // 16 KB
  const int t = threadIdx.x;
  const int lane = t & 63, wv = t >> 6;
  const int quad = lane >> 4, ml = lane & 15;
  const int m0 = blockIdx.x * 16;
  const int cw = wv * 48;

  {  // stage 16x512 x tile fp32 -> bf16, row-chunk XOR swizzle within kt-groups
    const int xr = t >> 4, c16 = t & 15;
    const float* xp = x + (size_t)(m0 + xr) * 512;
#pragma unroll
    for (int q = 0; q < 4; ++q) {
      int ch = q * 16 + c16;            // global 8-elt chunk 0-63
      int kt = ch >> 3, xc = ch & 7;
      int cb = xc ^ (xr & 7);
      float4 f0 = *(const float4*)(xp + ch * 8);
      float4 f1 = *(const float4*)(xp + ch * 8 + 4);
      *(uint4*)&xt[xr * 512 + (kt * 8 + cb) * 8] = pack8(f0, f1);
    }
  }
  __syncthreads();  // the only barrier in this kernel

  f32x4 acc[3];
#pragma unroll
  for (int j = 0; j < 3; ++j) acc[j] = (f32x4)0.0f;

  const u16* wp = wf + (size_t)(wv * 3) * 8192 + lane * 8;
  const int mlx = ml & 7;

  for (int kt = 0; kt < 8; ++kt) {
    short8 a[2], bfr[3][2];
#pragma unroll
    for (int kc = 0; kc < 2; ++kc)
      a[kc] = *(const short8*)
          &xt[ml * 512 + (kt * 8 + ((kc * 4 + quad) ^ mlx)) * 8];
#pragma unroll
    for (int nt = 0; nt < 3; ++nt)
#pragma unroll
      for (int kc = 0; kc < 2; ++kc)
        bfr[nt][kc] = *(const short8*)&wp[(size_t)nt * 8192 + kt * 1024 + kc * 512];
#pragma unroll
    for (int kc = 0; kc < 2; ++kc)
#pragma unroll
      for (int nt = 0; nt < 3; ++nt)
        acc[nt] = __builtin_amdgcn_mfma_f32_16x16x32_bf16(a[kc], bfr[nt][kc], acc[nt], 0, 0, 0);
  }
  // epilogue: C rows = quad*4+r, cols = lane&15
  const int mrow = m0 + quad * 4;
#pragma unroll
  for (int nt = 0; nt < 3; ++nt) {
    int n = cw + nt * 16 + ml;
    if (n < 128) {
      u16* dst = (n < 64) ? (Q + (size_t)mrow * 64 + n)
                          : (K + (size_t)mrow * 64 + (n - 64));
#pragma unroll
      for (int r = 0; r < 4; ++r) dst[(size_t)r * 64] = f2bf(acc[nt][r]);
    } else {
      int d = n - 128;
      int bb = m0 >> 11;
      int s0 = (m0 & 2047) + quad * 4;
      ushort4 pk;
      pk.x = f2bf(acc[nt][0]);
      pk.y = f2bf(acc[nt][1]);
      pk.z = f2bf(acc[nt][2]);
      pk.w = f2bf(acc[nt][3]);
      *(ushort4*)&V[((size_t)(bb * 64 + d)) * 2048 + s0] = pk;
    }
  }
}

// ---------------- Kernel 3: flash attention + output projection ----------------
// BYTE-IDENTICAL to round 8's passing kernel (120.5 us): 4 waves x 512 keys,
// K+V staged per-wave via gl_lds with source-pre-swizzle, barrier-free main
// loop, T13 defer-max, XCD-aware b = blk&7.
__global__ __launch_bounds__(256) void attn_out(
    const u16* __restrict__ Q, const u16* __restrict__ K,
    const u16* __restrict__ VT, const u16* __restrict__ WoT,
    float* __restrict__ out) {
  __shared__ __align__(16) char smem[65536];  // 64 KB: staging, then merge
  u16* kv = (u16*)smem;
  const int t = threadIdx.x, lane = t & 63, wv = t >> 6;
  const int lq = lane & 31, hi = lane >> 5;
  const int b = blockIdx.x & 7;             // XCD-local batch (T1)
  const int q0 = (blockIdx.x >> 3) * 32;
  u16* Kw = kv + wv * 8192;  // 64x64 bf16 K tile (8 KB)
  u16* Vw = Kw + 4096;       // 64x64 bf16 V^T tile (8 KB)

  // Q B-fragments: col = q = lq, k(d) = kc*16 + hi*8 + j
  const u16* Qb = Q + ((size_t)(b * 2048 + q0 + lq)) * 64 + hi * 8;
  short8 qf[4];
#pragma unroll
  for (int kc = 0; kc < 4; ++kc) qf[kc] = *(const short8*)&Qb[kc * 16];

  // staging lane geometry: lane covers (row = lane>>3, chunk = lane&7),
  // global chunk pre-swizzled so LDS[r][c] = G[r][c ^ (r&7)]
  const int lrow = lane >> 3;
  const int lcs = (lane & 7) ^ lrow;
  const u16* Kgl = K + ((size_t)(b * 2048 + wv * 512) * 64) + lrow * 64 + lcs * 8;
  const u16* Vgl = VT + ((size_t)(b * 64 + lrow) * 2048) + wv * 512 + lcs * 8;

#define STAGE(it_)                                                      \
  do {                                                                  \
    const u16* gk = Kgl + (size_t)(it_) * 4096;                         \
    const u16* gv = Vgl + (it_) * 64;                                   \
    _Pragma("unroll") for (int s_ = 0; s_ < 8; ++s_)                    \
        gl_lds16(gk + s_ * 512, Kw + s_ * 512);                         \
    _Pragma("unroll") for (int s_ = 0; s_ < 8; ++s_)                    \
        gl_lds16(gv + (size_t)s_ * 16384, Vw + s_ * 512);               \
  } while (0)

  f32x16 zt0 = (f32x16)0.0f, zt1 = (f32x16)0.0f;  // z^T: d rows, q = lq
  float m = -1e30f, l = 0.f;

  STAGE(0);

  for (int it = 0; it < 8; ++it) {
    asm volatile("s_waitcnt vmcnt(0)" ::: "memory");  // staged tile landed
    short8 ka[2][4];
#pragma unroll
    for (int kg = 0; kg < 2; ++kg)
#pragma unroll
      for (int kc = 0; kc < 4; ++kc)
        ka[kg][kc] = *(const short8*)&Kw[swo(kg * 32 + lq, kc * 2 + hi)];
    short8 va[2][4];
#pragma unroll
    for (int dt = 0; dt < 2; ++dt)
#pragma unroll
      for (int cc = 0; cc < 4; ++cc)
        va[dt][cc] = *(const short8*)&Vw[swo(dt * 32 + lq, cc * 2 + hi)];
    asm volatile("s_waitcnt lgkmcnt(0)" ::: "memory");  // frags in regs
    if (it < 7) STAGE(it + 1);  // prefetch hides under compute below

    // S^T[key][q] = K . Q
    f32x16 st0 = (f32x16)0.0f, st1 = (f32x16)0.0f;
    __builtin_amdgcn_s_setprio(1);
#pragma unroll
    for (int kc = 0; kc < 4; ++kc) {
      st0 = __builtin_amdgcn_mfma_f32_32x32x16_bf16(ka[0][kc], qf[kc], st0, 0, 0, 0);
      st1 = __builtin_amdgcn_mfma_f32_32x32x16_bf16(ka[1][kc], qf[kc], st1, 0, 0, 0);
    }
    __builtin_amdgcn_s_setprio(0);

    // lane-local softmax over 32 scores for q = lq (pair lane^32 has rest)
    float pm8[8];
#pragma unroll
    for (int r = 0; r < 8; ++r)
      pm8[r] = fmaxf(fmaxf(st0[r], st0[r + 8]), fmaxf(st1[r], st1[r + 8]));
    float pmax = fmaxf(fmaxf(fmaxf(pm8[0], pm8[1]), fmaxf(pm8[2], pm8[3])),
                       fmaxf(fmaxf(pm8[4], pm8[5]), fmaxf(pm8[6], pm8[7])));
    pmax = fmaxf(pmax, __shfl_xor(pmax, 32));
    if (!__all(pmax <= m + 8.f)) {  // defer-max (T13)
      float mnew = fmaxf(m, pmax);
      float alpha = __builtin_amdgcn_exp2f(m - mnew);
      m = mnew;
      l *= alpha;
#pragma unroll
      for (int r = 0; r < 16; ++r) {
        zt0[r] *= alpha;
        zt1[r] *= alpha;
      }
    }
    float rsa[4] = {0.f, 0.f, 0.f, 0.f};
#pragma unroll
    for (int r = 0; r < 16; ++r) {
      float p0 = __builtin_amdgcn_exp2f(st0[r] - m);
      float p1 = __builtin_amdgcn_exp2f(st1[r] - m);
      st0[r] = p0;
      st1[r] = p1;
      rsa[r & 3] += p0 + p1;
    }
    float rs = (rsa[0] + rsa[1]) + (rsa[2] + rsa[3]);
    rs += __shfl_xor(rs, 32);
    l += rs;

    // P -> bf16 B-fragments via cvt_pk + permlane32_swap (m214v22 recipe)
    short8 pa[4];
#pragma unroll
    for (int c = 0; c < 2; ++c) {
      {
        u32 u0 = cvtpk_bf16(st0[c * 8 + 0], st0[c * 8 + 1]);
        u32 u1 = cvtpk_bf16(st0[c * 8 + 2], st0[c * 8 + 3]);
        u32 u2 = cvtpk_bf16(st0[c * 8 + 4], st0[c * 8 + 5]);
        u32 u3 = cvtpk_bf16(st0[c * 8 + 6], st0[c * 8 + 7]);
        pl32swap(u0, u2);
        pl32swap(u1, u3);
        u32x4 uu;
        uu[0] = u0; uu[1] = u1; uu[2] = u2; uu[3] = u3;
        pa[c] = __builtin_bit_cast(short8, uu);
      }
      {
        u32 u0 = cvtpk_bf16(st1[c * 8 + 0], st1[c * 8 + 1]);
        u32 u1 = cvtpk_bf16(st1[c * 8 + 2], st1[c * 8 + 3]);
        u32 u2 = cvtpk_bf16(st1[c * 8 + 4], st1[c * 8 + 5]);
        u32 u3 = cvtpk_bf16(st1[c * 8 + 6], st1[c * 8 + 7]);
        pl32swap(u0, u2);
        pl32swap(u1, u3);
        u32x4 uu;
        uu[0] = u0; uu[1] = u1; uu[2] = u2; uu[3] = u3;
        pa[2 + c] = __builtin_bit_cast(short8, uu);
      }
    }

    // PV: z^T[d][q] += V^T[d][key] * P[key][q]
    __builtin_amdgcn_s_setprio(1);
#pragma unroll
    for (int cc = 0; cc < 4; ++cc) {
      zt0 = __builtin_amdgcn_mfma_f32_32x32x16_bf16(va[0][cc], pa[cc], zt0, 0, 0, 0);
      zt1 = __builtin_amdgcn_mfma_f32_32x32x16_bf16(va[1][cc], pa[cc], zt1, 0, 0, 0);
    }
    __builtin_amdgcn_s_setprio(0);
  }
#undef STAGE

  __syncthreads();  // all waves done with staging LDS; re-alias for merge
  float (*zp)[32][68] = (float (*)[32][68])smem;        // 34816 B
  float* mp = (float*)(smem + 34816);                   // [4][32]
  float* lp = (float*)(smem + 35328);                   // [4][32]
  u16* zb = (u16*)(smem + 35840);                       // [32][64]

#pragma unroll
  for (int r = 0; r < 16; ++r) {
    int d = (r & 3) + 8 * (r >> 2) + 4 * hi;
    zp[wv][lq][d] = zt0[r];
    zp[wv][lq][32 + d] = zt1[r];
  }
  if (hi == 0) {
    mp[wv * 32 + lq] = m;
    lp[wv * 32 + lq] = l;
  }
  __syncthreads();
  {  // merge 4 key-quarter partials; thread t -> (q = t>>3, 8 d's)
    int q = t >> 3, c8 = t & 7;
    float mv0 = mp[q], mv1 = mp[32 + q], mv2 = mp[64 + q], mv3 = mp[96 + q];
    float M = fmaxf(fmaxf(mv0, mv1), fmaxf(mv2, mv3));
    float aw[4];
    aw[0] = __builtin_amdgcn_exp2f(mv0 - M);
    aw[1] = __builtin_amdgcn_exp2f(mv1 - M);
    aw[2] = __builtin_amdgcn_exp2f(mv2 - M);
    aw[3] = __builtin_amdgcn_exp2f(mv3 - M);
    float L = aw[0] * lp[q] + aw[1] * lp[32 + q] + aw[2] * lp[64 + q] + aw[3] * lp[96 + q];
    float rl = 1.0f / L;
    f32x4 acc0 = (f32x4)0.0f, acc1 = (f32x4)0.0f;
#pragma unroll
    for (int w = 0; w < 4; ++w) {
      f32x4 z0 = *(const f32x4*)&zp[w][q][c8 * 8];
      f32x4 z1 = *(const f32x4*)&zp[w][q][c8 * 8 + 4];
      acc0 = acc0 + z0 * aw[w];
      acc1 = acc1 + z1 * aw[w];
    }
    acc0 = acc0 * rl;
    acc1 = acc1 * rl;
    short8 pk;
#pragma unroll
    for (int j = 0; j < 4; ++j) {
      pk[j] = (short)f2bf(acc0[j]);
      pk[4 + j] = (short)f2bf(acc1[j]);
    }
    *(short8*)&zb[q * 64 + ((c8 ^ (q & 7)) * 8)] = pk;
  }
  __syncthreads();
  // fused output projection: out[32 q][512] = z[32][64] @ WoSum[64][512]
  const int quad = lane >> 4, ml = lane & 15;
  short8 zf[2][2];
#pragma unroll
  for (int sub = 0; sub < 2; ++sub)
#pragma unroll
    for (int kc = 0; kc < 2; ++kc)
      zf[sub][kc] = *(const short8*)&zb[swo(sub * 16 + ml, kc * 4 + quad)];
  const size_t ob = (size_t)(b * 2048 + q0);
#pragma unroll
  for (int nt2 = 0; nt2 < 8; ++nt2) {
    int col0 = wv * 128 + nt2 * 16;
    short8 wb0 = *(const short8*)&WoT[(size_t)(col0 + ml) * 64 + quad * 8];
    short8 wb1 = *(const short8*)&WoT[(size_t)(col0 + ml) * 64 + 32 + quad * 8];
#pragma unroll
    for (int sub = 0; sub < 2; ++sub) {
      f32x4 o = (f32x4)0.0f;
      o = __builtin_amdgcn_mfma_f32_16x16x32_bf16(zf[sub][0], wb0, o, 0, 0, 0);
      o = __builtin_amdgcn_mfma_f32_16x16x32_bf16(zf[sub][1], wb1, o, 0, 0, 0);
#pragma unroll
      for (int r = 0; r < 4; ++r)
        out[(ob + sub * 16 + quad * 4 + r) * 512 + col0 + ml] = o[r];
    }
  }
}

extern "C" void kernel_launch(void* const* d_in, const int* in_sizes, int n_in,
                              void* d_out, int out_size, void* d_ws, size_t ws_size,
                              hipStream_t stream) {
  const float* x = (const float*)d_in[0];
  const float* Wq = (const float*)d_in[1];
  const float* Wk = (const float*)d_in[2];
  const float* Wv = (const float*)d_in[3];
  const float* Wo = (const float*)d_in[4];
  float* out = (float*)d_out;

  u16* wf = (u16*)d_ws;            // [12][8][2][64][8] fragment-contiguous W
  u16* wot = wf + 192 * 512;       // [512][64]
  u16* Q = wot + 512 * 64;         // [16384][64]
  u16* K = Q + 16384 * 64;         // [16384][64]
  u16* V = K + 16384 * 64;         // [8][64][2048] (V^T per batch)

  hipLaunchKernelGGL(prep, dim3(512), dim3(256), 0, stream, Wq, Wk, Wv, Wo, wf, wot);
  hipLaunchKernelGGL(qkv_proj, dim3(1024), dim3(256), 0, stream, x, wf, Q, K, V);
  hipLaunchKernelGGL(attn_out, dim3(512), dim3(256), 0, stream, Q, K, V, wot, out);
}

// Round 11
// 120.701 us; speedup vs baseline: 1.0246x; 1.0246x over previous
//
#include <hip/hip_runtime.h>

typedef unsigned short u16;
typedef unsigned int u32;
typedef unsigned long long uptr;
typedef __attribute__((ext_vector_type(8))) short short8;
typedef __attribute__((ext_vector_type(4))) float f32x4;
typedef __attribute__((ext_vector_type(16))) float f32x16;
typedef __attribute__((ext_vector_type(4))) u32 u32x4;

#define LOG2E 1.4426950408889634f
#define RSQRT_MD 0.04419417382415922f

__device__ __forceinline__ u16 f2bf(float f) {
  u32 u = __builtin_bit_cast(u32, f);
  u32 r = u + 0x7fffu + ((u >> 16) & 1u);
  return (u16)(r >> 16);
}

__device__ __forceinline__ uint4 pack8(float4 a, float4 b) {
  uint4 c;
  c.x = (u32)f2bf(a.x) | ((u32)f2bf(a.y) << 16);
  c.y = (u32)f2bf(a.z) | ((u32)f2bf(a.w) << 16);
  c.z = (u32)f2bf(b.x) | ((u32)f2bf(b.y) << 16);
  c.w = (u32)f2bf(b.z) | ((u32)f2bf(b.w) << 16);
  return c;
}

// v_cvt_pk_bf16_f32: packs (a -> low bf16, b -> high bf16), RNE
__device__ __forceinline__ u32 cvtpk_bf16(float a, float b) {
  u32 r;
  asm("v_cvt_pk_bf16_f32 %0, %1, %2" : "=v"(r) : "v"(a), "v"(b));
  return r;
}

// v_permlane32_swap_b32: a' = [a.lo|b.lo], b' = [a.hi|b.hi]
__device__ __forceinline__ void pl32swap(u32& a, u32& b) {
  asm volatile("v_permlane32_swap_b32 %0, %1" : "+v"(a), "+v"(b));
}

// LDS tile: rows of 64 bf16 = 8 chunks of 16B, chunk XOR-swizzled by row&7
__device__ __forceinline__ int swo(int row, int chunk) {
  return row * 64 + ((chunk ^ (row & 7)) * 8);
}

// async global->LDS, 16B per lane; LDS dest = wave-uniform base + lane*16
__device__ __forceinline__ void gl_lds16(const u16* g, u16* l) {
  auto gp = (const __attribute__((address_space(1))) u16*)(uptr)g;
  auto lp = (__attribute__((address_space(3))) u16*)(uptr)l;
  __builtin_amdgcn_global_load_lds(gp, lp, 16, 0, 0);
}

// ---------------- Kernel 1: weight prep ----------------
// wf[nt_g(12)][kt(8)][kc(2)][lane(64)][8] bf16 fragment-contiguous QKV weights;
// wot[512][64] bf16 WoSum^T. (unchanged)
__global__ __launch_bounds__(256) void prep(
    const float* __restrict__ Wq, const float* __restrict__ Wk,
    const float* __restrict__ Wv, const float* __restrict__ Wo,
    u16* __restrict__ wf, u16* __restrict__ wot) {
  int idx = blockIdx.x * 256 + threadIdx.x;
  if (idx < 3 * 64 * 512) {
    int row = idx >> 9, k = idx & 511;
    int mat = row >> 6, n = row & 63;
    const float* W = (mat == 0) ? Wq : ((mat == 1) ? Wk : Wv);
    float scale = (mat == 0) ? (LOG2E * RSQRT_MD) : 1.0f;
    u16 v = f2bf(W[k * 64 + n] * scale);
    int nt_g = row >> 4, ml = row & 15;
    int kt = k >> 6, kc = (k >> 5) & 1, quad = (k >> 3) & 3, j = k & 7;
    wf[((((nt_g * 8 + kt) * 2 + kc) * 64) + quad * 16 + ml) * 8 + j] = v;
  } else {
    int j = idx - 3 * 64 * 512;
    int d = j >> 6, e = j & 63;
    float s = 0.f;
#pragma unroll
    for (int h = 0; h < 8; ++h) s += Wo[(size_t)(h * 64 + e) * 512 + d];
    wot[j] = f2bf(s);
  }
}

// ---------------- Kernel 2: QKV projection ----------------
// R4/R8 proven version: 32-row tiles, grid 512; x staged once to LDS, single
// barrier, W fragments from the fragment-contiguous wf table, barrier-free
// K-loop. (R10's 16-row/grid-1024 variant was +3 us: doubled wf L2 traffic.)
__global__ __launch_bounds__(256) void qkv_proj(
    const float* __restrict__ x, const u16* __restrict__ wf,
    u16* __restrict__ Q, u16* __restrict__ K, u16* __restrict__ V) {
  __shared__ __align__(16) u16 xt[32 * 512];  // 32 KB
  const int t = threadIdx.x;
  const int lane = t & 63, wv = t >> 6;
  const int quad = lane >> 4, ml = lane & 15;
  const int m0 = blockIdx.x * 32;
  const int cw = wv * 48;

  {  // stage whole 32x512 x tile fp32 -> bf16, row-chunk XOR swizzle
    const int xr = t >> 3, xc = t & 7;
    const float* xp = x + (size_t)(m0 + xr) * 512 + xc * 8;
    const int cb = xc ^ (xr & 7);
#pragma unroll
    for (int kt = 0; kt < 8; ++kt) {
      float4 f0 = *(const float4*)(xp + kt * 64);
      float4 f1 = *(const float4*)(xp + kt * 64 + 4);
      *(uint4*)&xt[xr * 512 + (kt * 8 + cb) * 8] = pack8(f0, f1);
    }
  }
  __syncthreads();  // the only barrier in this kernel

  f32x4 acc[2][3];
#pragma unroll
  for (int i = 0; i < 2; ++i)
#pragma unroll
    for (int j = 0; j < 3; ++j) acc[i][j] = (f32x4)0.0f;

  const u16* wp = wf + (size_t)(wv * 3) * 8192 + lane * 8;
  const int mlx = ml & 7;

  for (int kt = 0; kt < 8; ++kt) {
    short8 a[2][2], b[3][2];
#pragma unroll
    for (int sub = 0; sub < 2; ++sub)
#pragma unroll
      for (int kc = 0; kc < 2; ++kc)
        a[sub][kc] = *(const short8*)
            &xt[(sub * 16 + ml) * 512 + (kt * 8 + ((kc * 4 + quad) ^ mlx)) * 8];
#pragma unroll
    for (int nt = 0; nt < 3; ++nt)
#pragma unroll
      for (int kc = 0; kc < 2; ++kc)
        b[nt][kc] = *(const short8*)&wp[(size_t)nt * 8192 + kt * 1024 + kc * 512];
#pragma unroll
    for (int kc = 0; kc < 2; ++kc)
#pragma unroll
      for (int sub = 0; sub < 2; ++sub)
#pragma unroll
        for (int nt = 0; nt < 3; ++nt)
          acc[sub][nt] = __builtin_amdgcn_mfma_f32_16x16x32_bf16(a[sub][kc], b[nt][kc], acc[sub][nt], 0, 0, 0);
  }
#pragma unroll
  for (int sub = 0; sub < 2; ++sub) {
    const int mrow = m0 + sub * 16 + quad * 4;
#pragma unroll
    for (int nt = 0; nt < 3; ++nt) {
      int n = cw + nt * 16 + ml;
      if (n < 128) {
        u16* dst = (n < 64) ? (Q + (size_t)mrow * 64 + n)
                            : (K + (size_t)mrow * 64 + (n - 64));
#pragma unroll
        for (int r = 0; r < 4; ++r) dst[(size_t)r * 64] = f2bf(acc[sub][nt][r]);
      } else {
        int d = n - 128;
        int bb = m0 >> 11;
        int s0 = (m0 & 2047) + sub * 16 + quad * 4;
        ushort4 pk;
        pk.x = f2bf(acc[sub][nt][0]);
        pk.y = f2bf(acc[sub][nt][1]);
        pk.z = f2bf(acc[sub][nt][2]);
        pk.w = f2bf(acc[sub][nt][3]);
        *(ushort4*)&V[((size_t)(bb * 64 + d)) * 2048 + s0] = pk;
      }
    }
  }
}

// ---------------- Kernel 3: flash attention + output projection ----------------
// R8 structure (4 waves x 512 keys, K+V staged per-wave via gl_lds, T13
// defer-max, XCD-aware b = blk&7) with ONE change: counted-vmcnt software
// pipeline (T4). K and V waits are split: vmcnt(8) for K -> QK^T overlaps V
// landing; STAGE_K(it+1) issued before QK^T, STAGE_V(it+1) before softmax/PV
// -> next tile's loads get a full compute phase to land. Never vmcnt(0) in
// the main loop (only last iter). WAR on the single buffer protected by
// lgkmcnt(0) before each STAGE half.
__global__ __launch_bounds__(256) void attn_out(
    const u16* __restrict__ Q, const u16* __restrict__ K,
    const u16* __restrict__ VT, const u16* __restrict__ WoT,
    float* __restrict__ out) {
  __shared__ __align__(16) char smem[65536];  // 64 KB: staging, then merge
  u16* kv = (u16*)smem;
  const int t = threadIdx.x, lane = t & 63, wv = t >> 6;
  const int lq = lane & 31, hi = lane >> 5;
  const int b = blockIdx.x & 7;             // XCD-local batch (T1)
  const int q0 = (blockIdx.x >> 3) * 32;
  u16* Kw = kv + wv * 8192;  // 64x64 bf16 K tile (8 KB)
  u16* Vw = Kw + 4096;       // 64x64 bf16 V^T tile (8 KB)

  // Q B-fragments: col = q = lq, k(d) = kc*16 + hi*8 + j
  const u16* Qb = Q + ((size_t)(b * 2048 + q0 + lq)) * 64 + hi * 8;
  short8 qf[4];
#pragma unroll
  for (int kc = 0; kc < 4; ++kc) qf[kc] = *(const short8*)&Qb[kc * 16];

  // staging lane geometry: lane covers (row = lane>>3, chunk = lane&7),
  // global chunk pre-swizzled so LDS[r][c] = G[r][c ^ (r&7)]
  const int lrow = lane >> 3;
  const int lcs = (lane & 7) ^ lrow;
  const u16* Kgl = K + ((size_t)(b * 2048 + wv * 512) * 64) + lrow * 64 + lcs * 8;
  const u16* Vgl = VT + ((size_t)(b * 64 + lrow) * 2048) + wv * 512 + lcs * 8;

#define STAGEK(it_)                                                     \
  do {                                                                  \
    const u16* gk = Kgl + (size_t)(it_) * 4096;                         \
    _Pragma("unroll") for (int s_ = 0; s_ < 8; ++s_)                    \
        gl_lds16(gk + s_ * 512, Kw + s_ * 512);                         \
  } while (0)
#define STAGEV(it_)                                                     \
  do {                                                                  \
    const u16* gv = Vgl + (it_) * 64;                                   \
    _Pragma("unroll") for (int s_ = 0; s_ < 8; ++s_)                    \
        gl_lds16(gv + (size_t)s_ * 16384, Vw + s_ * 512);               \
  } while (0)

  f32x16 zt0 = (f32x16)0.0f, zt1 = (f32x16)0.0f;  // z^T: d rows, q = lq
  float m = -1e30f, l = 0.f;

  STAGEK(0);
  STAGEV(0);

  for (int it = 0; it < 8; ++it) {
    // K tile landed (V still in flight: 8 outstanding)
    asm volatile("s_waitcnt vmcnt(8)" ::: "memory");
    short8 ka[2][4];
#pragma unroll
    for (int kg = 0; kg < 2; ++kg)
#pragma unroll
      for (int kc = 0; kc < 4; ++kc)
        ka[kg][kc] = *(const short8*)&Kw[swo(kg * 32 + lq, kc * 2 + hi)];
    asm volatile("s_waitcnt lgkmcnt(0)" ::: "memory");  // ka in regs (WAR)
    if (it < 7) STAGEK(it + 1);  // issue next K; lands during softmax+PV

    // S^T[key][q] = K . Q  -- overlaps V(it) landing
    f32x16 st0 = (f32x16)0.0f, st1 = (f32x16)0.0f;
    __builtin_amdgcn_s_setprio(1);
#pragma unroll
    for (int kc = 0; kc < 4; ++kc) {
      st0 = __builtin_amdgcn_mfma_f32_32x32x16_bf16(ka[0][kc], qf[kc], st0, 0, 0, 0);
      st1 = __builtin_amdgcn_mfma_f32_32x32x16_bf16(ka[1][kc], qf[kc], st1, 0, 0, 0);
    }
    __builtin_amdgcn_s_setprio(0);

    // V tile landed (K(it+1) still in flight when it<7)
    if (it < 7)
      asm volatile("s_waitcnt vmcnt(8)" ::: "memory");
    else
      asm volatile("s_waitcnt vmcnt(0)" ::: "memory");
    short8 va[2][4];
#pragma unroll
    for (int dt = 0; dt < 2; ++dt)
#pragma unroll
      for (int cc = 0; cc < 4; ++cc)
        va[dt][cc] = *(const short8*)&Vw[swo(dt * 32 + lq, cc * 2 + hi)];
    asm volatile("s_waitcnt lgkmcnt(0)" ::: "memory");  // va in regs (WAR)
    if (it < 7) STAGEV(it + 1);  // issue next V; lands during next QK^T

    // lane-local softmax over 32 scores for q = lq (pair lane^32 has rest)
    float pm8[8];
#pragma unroll
    for (int r = 0; r < 8; ++r)
      pm8[r] = fmaxf(fmaxf(st0[r], st0[r + 8]), fmaxf(st1[r], st1[r + 8]));
    float pmax = fmaxf(fmaxf(fmaxf(pm8[0], pm8[1]), fmaxf(pm8[2], pm8[3])),
                       fmaxf(fmaxf(pm8[4], pm8[5]), fmaxf(pm8[6], pm8[7])));
    pmax = fmaxf(pmax, __shfl_xor(pmax, 32));
    if (!__all(pmax <= m + 8.f)) {  // defer-max (T13)
      float mnew = fmaxf(m, pmax);
      float alpha = __builtin_amdgcn_exp2f(m - mnew);
      m = mnew;
      l *= alpha;
#pragma unroll
      for (int r = 0; r < 16; ++r) {
        zt0[r] *= alpha;
        zt1[r] *= alpha;
      }
    }
    float rsa[4] = {0.f, 0.f, 0.f, 0.f};
#pragma unroll
    for (int r = 0; r < 16; ++r) {
      float p0 = __builtin_amdgcn_exp2f(st0[r] - m);
      float p1 = __builtin_amdgcn_exp2f(st1[r] - m);
      st0[r] = p0;
      st1[r] = p1;
      rsa[r & 3] += p0 + p1;
    }
    float rs = (rsa[0] + rsa[1]) + (rsa[2] + rsa[3]);
    rs += __shfl_xor(rs, 32);
    l += rs;

    // P -> bf16 B-fragments via cvt_pk + permlane32_swap (m214v22 recipe)
    short8 pa[4];
#pragma unroll
    for (int c = 0; c < 2; ++c) {
      {
        u32 u0 = cvtpk_bf16(st0[c * 8 + 0], st0[c * 8 + 1]);
        u32 u1 = cvtpk_bf16(st0[c * 8 + 2], st0[c * 8 + 3]);
        u32 u2 = cvtpk_bf16(st0[c * 8 + 4], st0[c * 8 + 5]);
        u32 u3 = cvtpk_bf16(st0[c * 8 + 6], st0[c * 8 + 7]);
        pl32swap(u0, u2);
        pl32swap(u1, u3);
        u32x4 uu;
        uu[0] = u0; uu[1] = u1; uu[2] = u2; uu[3] = u3;
        pa[c] = __builtin_bit_cast(short8, uu);
      }
      {
        u32 u0 = cvtpk_bf16(st1[c * 8 + 0], st1[c * 8 + 1]);
        u32 u1 = cvtpk_bf16(st1[c * 8 + 2], st1[c * 8 + 3]);
        u32 u2 = cvtpk_bf16(st1[c * 8 + 4], st1[c * 8 + 5]);
        u32 u3 = cvtpk_bf16(st1[c * 8 + 6], st1[c * 8 + 7]);
        pl32swap(u0, u2);
        pl32swap(u1, u3);
        u32x4 uu;
        uu[0] = u0; uu[1] = u1; uu[2] = u2; uu[3] = u3;
        pa[2 + c] = __builtin_bit_cast(short8, uu);
      }
    }

    // PV: z^T[d][q] += V^T[d][key] * P[key][q]
    __builtin_amdgcn_s_setprio(1);
#pragma unroll
    for (int cc = 0; cc < 4; ++cc) {
      zt0 = __builtin_amdgcn_mfma_f32_32x32x16_bf16(va[0][cc], pa[cc], zt0, 0, 0, 0);
      zt1 = __builtin_amdgcn_mfma_f32_32x32x16_bf16(va[1][cc], pa[cc], zt1, 0, 0, 0);
    }
    __builtin_amdgcn_s_setprio(0);
  }
#undef STAGEK
#undef STAGEV

  __syncthreads();  // all waves done with staging LDS; re-alias for merge
  float (*zp)[32][68] = (float (*)[32][68])smem;        // 34816 B
  float* mp = (float*)(smem + 34816);                   // [4][32]
  float* lp = (float*)(smem + 35328);                   // [4][32]
  u16* zb = (u16*)(smem + 35840);                       // [32][64]

#pragma unroll
  for (int r = 0; r < 16; ++r) {
    int d = (r & 3) + 8 * (r >> 2) + 4 * hi;
    zp[wv][lq][d] = zt0[r];
    zp[wv][lq][32 + d] = zt1[r];
  }
  if (hi == 0) {
    mp[wv * 32 + lq] = m;
    lp[wv * 32 + lq] = l;
  }
  __syncthreads();
  {  // merge 4 key-quarter partials; thread t -> (q = t>>3, 8 d's)
    int q = t >> 3, c8 = t & 7;
    float mv0 = mp[q], mv1 = mp[32 + q], mv2 = mp[64 + q], mv3 = mp[96 + q];
    float M = fmaxf(fmaxf(mv0, mv1), fmaxf(mv2, mv3));
    float aw[4];
    aw[0] = __builtin_amdgcn_exp2f(mv0 - M);
    aw[1] = __builtin_amdgcn_exp2f(mv1 - M);
    aw[2] = __builtin_amdgcn_exp2f(mv2 - M);
    aw[3] = __builtin_amdgcn_exp2f(mv3 - M);
    float L = aw[0] * lp[q] + aw[1] * lp[32 + q] + aw[2] * lp[64 + q] + aw[3] * lp[96 + q];
    float rl = 1.0f / L;
    f32x4 acc0 = (f32x4)0.0f, acc1 = (f32x4)0.0f;
#pragma unroll
    for (int w = 0; w < 4; ++w) {
      f32x4 z0 = *(const f32x4*)&zp[w][q][c8 * 8];
      f32x4 z1 = *(const f32x4*)&zp[w][q][c8 * 8 + 4];
      acc0 = acc0 + z0 * aw[w];
      acc1 = acc1 + z1 * aw[w];
    }
    acc0 = acc0 * rl;
    acc1 = acc1 * rl;
    short8 pk;
#pragma unroll
    for (int j = 0; j < 4; ++j) {
      pk[j] = (short)f2bf(acc0[j]);
      pk[4 + j] = (short)f2bf(acc1[j]);
    }
    *(short8*)&zb[q * 64 + ((c8 ^ (q & 7)) * 8)] = pk;
  }
  __syncthreads();
  // fused output projection: out[32 q][512] = z[32][64] @ WoSum[64][512]
  const int quad = lane >> 4, ml = lane & 15;
  short8 zf[2][2];
#pragma unroll
  for (int sub = 0; sub < 2; ++sub)
#pragma unroll
    for (int kc = 0; kc < 2; ++kc)
      zf[sub][kc] = *(const short8*)&zb[swo(sub * 16 + ml, kc * 4 + quad)];
  const size_t ob = (size_t)(b * 2048 + q0);
#pragma unroll
  for (int nt2 = 0; nt2 < 8; ++nt2) {
    int col0 = wv * 128 + nt2 * 16;
    short8 wb0 = *(const short8*)&WoT[(size_t)(col0 + ml) * 64 + quad * 8];
    short8 wb1 = *(const short8*)&WoT[(size_t)(col0 + ml) * 64 + 32 + quad * 8];
#pragma unroll
    for (int sub = 0; sub < 2; ++sub) {
      f32x4 o = (f32x4)0.0f;
      o = __builtin_amdgcn_mfma_f32_16x16x32_bf16(zf[sub][0], wb0, o, 0, 0, 0);
      o = __builtin_amdgcn_mfma_f32_16x16x32_bf16(zf[sub][1], wb1, o, 0, 0, 0);
#pragma unroll
      for (int r = 0; r < 4; ++r)
        out[(ob + sub * 16 + quad * 4 + r) * 512 + col0 + ml] = o[r];
    }
  }
}

extern "C" void kernel_launch(void* const* d_in, const int* in_sizes, int n_in,
                              void* d_out, int out_size, void* d_ws, size_t ws_size,
                              hipStream_t stream) {
  const float* x = (const float*)d_in[0];
  const float* Wq = (const float*)d_in[1];
  const float* Wk = (const float*)d_in[2];
  const float* Wv = (const float*)d_in[3];
  const float* Wo = (const float*)d_in[4];
  float* out = (float*)d_out;

  u16* wf = (u16*)d_ws;            // [12][8][2][64][8] fragment-contiguous W
  u16* wot = wf + 192 * 512;       // [512][64]
  u16* Q = wot + 512 * 64;         // [16384][64]
  u16* K = Q + 16384 * 64;         // [16384][64]
  u16* V = K + 16384 * 64;         // [8][64][2048] (V^T per batch)

  hipLaunchKernelGGL(prep, dim3(512), dim3(256), 0, stream, Wq, Wk, Wv, Wo, wf, wot);
  hipLaunchKernelGGL(qkv_proj, dim3(512), dim3(256), 0, stream, x, wf, Q, K, V);
  hipLaunchKernelGGL(attn_out, dim3(512), dim3(256), 0, stream, Q, K, V, wot, out);
}

// Round 12
// 118.210 us; speedup vs baseline: 1.0462x; 1.0211x over previous
//
#include <hip/hip_runtime.h>

typedef unsigned short u16;
typedef unsigned int u32;
typedef unsigned long long uptr;
typedef __attribute__((ext_vector_type(8))) short short8;
typedef __attribute__((ext_vector_type(4))) float f32x4;
typedef __attribute__((ext_vector_type(16))) float f32x16;
typedef __attribute__((ext_vector_type(4))) u32 u32x4;

#define LOG2E 1.4426950408889634f
#define RSQRT_MD 0.04419417382415922f

__device__ __forceinline__ u16 f2bf(float f) {
  u32 u = __builtin_bit_cast(u32, f);
  u32 r = u + 0x7fffu + ((u >> 16) & 1u);
  return (u16)(r >> 16);
}

__device__ __forceinline__ uint4 pack8(float4 a, float4 b) {
  uint4 c;
  c.x = (u32)f2bf(a.x) | ((u32)f2bf(a.y) << 16);
  c.y = (u32)f2bf(a.z) | ((u32)f2bf(a.w) << 16);
  c.z = (u32)f2bf(b.x) | ((u32)f2bf(b.y) << 16);
  c.w = (u32)f2bf(b.z) | ((u32)f2bf(b.w) << 16);
  return c;
}

// v_cvt_pk_bf16_f32: packs (a -> low bf16, b -> high bf16), RNE
__device__ __forceinline__ u32 cvtpk_bf16(float a, float b) {
  u32 r;
  asm("v_cvt_pk_bf16_f32 %0, %1, %2" : "=v"(r) : "v"(a), "v"(b));
  return r;
}

// v_permlane32_swap_b32: a' = [a.lo|b.lo], b' = [a.hi|b.hi]
__device__ __forceinline__ void pl32swap(u32& a, u32& b) {
  asm volatile("v_permlane32_swap_b32 %0, %1" : "+v"(a), "+v"(b));
}

// LDS tile: rows of 64 bf16 = 8 chunks of 16B, chunk XOR-swizzled by row&7
__device__ __forceinline__ int swo(int row, int chunk) {
  return row * 64 + ((chunk ^ (row & 7)) * 8);
}

// async global->LDS, 16B per lane; LDS dest = wave-uniform base + lane*16
__device__ __forceinline__ void gl_lds16(const u16* g, u16* l) {
  auto gp = (const __attribute__((address_space(1))) u16*)(uptr)g;
  auto lp = (__attribute__((address_space(3))) u16*)(uptr)l;
  __builtin_amdgcn_global_load_lds(gp, lp, 16, 0, 0);
}

// ---------------- Kernel 1: weight prep ----------------
// wf[nt_g(12)][kt(8)][kc(2)][lane(64)][8] bf16 fragment-contiguous QKV weights;
// wot[512][64] bf16 WoSum^T. (unchanged)
__global__ __launch_bounds__(256) void prep(
    const float* __restrict__ Wq, const float* __restrict__ Wk,
    const float* __restrict__ Wv, const float* __restrict__ Wo,
    u16* __restrict__ wf, u16* __restrict__ wot) {
  int idx = blockIdx.x * 256 + threadIdx.x;
  if (idx < 3 * 64 * 512) {
    int row = idx >> 9, k = idx & 511;
    int mat = row >> 6, n = row & 63;
    const float* W = (mat == 0) ? Wq : ((mat == 1) ? Wk : Wv);
    float scale = (mat == 0) ? (LOG2E * RSQRT_MD) : 1.0f;
    u16 v = f2bf(W[k * 64 + n] * scale);
    int nt_g = row >> 4, ml = row & 15;
    int kt = k >> 6, kc = (k >> 5) & 1, quad = (k >> 3) & 3, j = k & 7;
    wf[((((nt_g * 8 + kt) * 2 + kc) * 64) + quad * 16 + ml) * 8 + j] = v;
  } else {
    int j = idx - 3 * 64 * 512;
    int d = j >> 6, e = j & 63;
    float s = 0.f;
#pragma unroll
    for (int h = 0; h < 8; ++h) s += Wo[(size_t)(h * 64 + e) * 512 + d];
    wot[j] = f2bf(s);
  }
}

// ---------------- Kernel 2: QKV projection ----------------
// (byte-identical to R8/R11: 32-row tiles, grid 512; x staged once, single
// barrier, W fragments from the fragment-contiguous wf table)
__global__ __launch_bounds__(256) void qkv_proj(
    const float* __restrict__ x, const u16* __restrict__ wf,
    u16* __restrict__ Q, u16* __restrict__ K, u16* __restrict__ V) {
  __shared__ __align__(16) u16 xt[32 * 512];  // 32 KB
  const int t = threadIdx.x;
  const int lane = t & 63, wv = t >> 6;
  const int quad = lane >> 4, ml = lane & 15;
  const int m0 = blockIdx.x * 32;
  const int cw = wv * 48;

  {  // stage whole 32x512 x tile fp32 -> bf16, row-chunk XOR swizzle
    const int xr = t >> 3, xc = t & 7;
    const float* xp = x + (size_t)(m0 + xr) * 512 + xc * 8;
    const int cb = xc ^ (xr & 7);
#pragma unroll
    for (int kt = 0; kt < 8; ++kt) {
      float4 f0 = *(const float4*)(xp + kt * 64);
      float4 f1 = *(const float4*)(xp + kt * 64 + 4);
      *(uint4*)&xt[xr * 512 + (kt * 8 + cb) * 8] = pack8(f0, f1);
    }
  }
  __syncthreads();  // the only barrier in this kernel

  f32x4 acc[2][3];
#pragma unroll
  for (int i = 0; i < 2; ++i)
#pragma unroll
    for (int j = 0; j < 3; ++j) acc[i][j] = (f32x4)0.0f;

  const u16* wp = wf + (size_t)(wv * 3) * 8192 + lane * 8;
  const int mlx = ml & 7;

  for (int kt = 0; kt < 8; ++kt) {
    short8 a[2][2], b[3][2];
#pragma unroll
    for (int sub = 0; sub < 2; ++sub)
#pragma unroll
      for (int kc = 0; kc < 2; ++kc)
        a[sub][kc] = *(const short8*)
            &xt[(sub * 16 + ml) * 512 + (kt * 8 + ((kc * 4 + quad) ^ mlx)) * 8];
#pragma unroll
    for (int nt = 0; nt < 3; ++nt)
#pragma unroll
      for (int kc = 0; kc < 2; ++kc)
        b[nt][kc] = *(const short8*)&wp[(size_t)nt * 8192 + kt * 1024 + kc * 512];
#pragma unroll
    for (int kc = 0; kc < 2; ++kc)
#pragma unroll
      for (int sub = 0; sub < 2; ++sub)
#pragma unroll
        for (int nt = 0; nt < 3; ++nt)
          acc[sub][nt] = __builtin_amdgcn_mfma_f32_16x16x32_bf16(a[sub][kc], b[nt][kc], acc[sub][nt], 0, 0, 0);
  }
#pragma unroll
  for (int sub = 0; sub < 2; ++sub) {
    const int mrow = m0 + sub * 16 + quad * 4;
#pragma unroll
    for (int nt = 0; nt < 3; ++nt) {
      int n = cw + nt * 16 + ml;
      if (n < 128) {
        u16* dst = (n < 64) ? (Q + (size_t)mrow * 64 + n)
                            : (K + (size_t)mrow * 64 + (n - 64));
#pragma unroll
        for (int r = 0; r < 4; ++r) dst[(size_t)r * 64] = f2bf(acc[sub][nt][r]);
      } else {
        int d = n - 128;
        int bb = m0 >> 11;
        int s0 = (m0 & 2047) + sub * 16 + quad * 4;
        ushort4 pk;
        pk.x = f2bf(acc[sub][nt][0]);
        pk.y = f2bf(acc[sub][nt][1]);
        pk.z = f2bf(acc[sub][nt][2]);
        pk.w = f2bf(acc[sub][nt][3]);
        *(ushort4*)&V[((size_t)(bb * 64 + d)) * 2048 + s0] = pk;
      }
    }
  }
}

// ---------------- Kernel 3: flash attention + output projection ----------------
// K/V-traffic-halving rework: grid 256 x 8 waves, 64 q-rows per block.
// Wave (quarter=wv>>1, qg=wv&1): per-wave math is VERBATIM R8 (32 q x 512
// keys, 8 iters of 64, swapped-QK^T 32x32, T13 defer-max, cvt_pk+permlane).
// The two waves of a pair share double-buffered K/V tiles (2 x 16 KB/pair,
// 128 KiB LDS total -> 1 block/CU x 8 waves = 2 waves/SIMD, same as R8):
// K-wave (qg=0) stages K, V-wave stages V into the alt buffer right after the
// lgkm drain; one __syncthreads per iter (implicit vmcnt(0) = landing
// guarantee, a full compute phase of DMA overlap). Halves K/V L2 reads
// (268 -> 134 MB). Merge = R8 merge over [4][64] partials; out-proj 64 rows.
__global__ __launch_bounds__(512) void attn_out(
    const u16* __restrict__ Q, const u16* __restrict__ K,
    const u16* __restrict__ VT, const u16* __restrict__ WoT,
    float* __restrict__ out) {
  __shared__ __align__(16) char smem[131072];  // 4 pairs x 2 bufs x 16 KB; merge aliases
  u16* kv = (u16*)smem;
  const int t = threadIdx.x, lane = t & 63, wv = t >> 6;  // wv 0..7
  const int lq = lane & 31, hi = lane >> 5;
  const int quarter = wv >> 1;   // key quarter (512 keys)
  const int qg = wv & 1;         // q-row group (32 rows)
  const int b = blockIdx.x & 7;             // XCD-local batch (T1)
  const int q0 = (blockIdx.x >> 3) * 64;
  u16* pairbase = kv + quarter * 16384;     // 2 buffers of 8192 u16 each

  // Q B-fragments: col = q = lq (of this wave's 32-row group)
  const u16* Qb = Q + ((size_t)(b * 2048 + q0 + qg * 32 + lq)) * 64 + hi * 8;
  short8 qf[4];
#pragma unroll
  for (int kc = 0; kc < 4; ++kc) qf[kc] = *(const short8*)&Qb[kc * 16];

  // staging lane geometry: lane covers (row = lane>>3, chunk = lane&7),
  // global chunk pre-swizzled so LDS[r][c] = G[r][c ^ (r&7)]
  const int lrow = lane >> 3;
  const int lcs = (lane & 7) ^ lrow;
  const u16* Kgl = K + ((size_t)(b * 2048 + quarter * 512) * 64) + lrow * 64 + lcs * 8;
  const u16* Vgl = VT + ((size_t)(b * 64 + lrow) * 2048) + quarter * 512 + lcs * 8;

#define STAGEK(it_, dst_)                                               \
  do {                                                                  \
    const u16* gk = Kgl + (size_t)(it_) * 4096;                         \
    _Pragma("unroll") for (int s_ = 0; s_ < 8; ++s_)                    \
        gl_lds16(gk + s_ * 512, (dst_) + s_ * 512);                     \
  } while (0)
#define STAGEV(it_, dst_)                                               \
  do {                                                                  \
    const u16* gv = Vgl + (it_) * 64;                                   \
    _Pragma("unroll") for (int s_ = 0; s_ < 8; ++s_)                    \
        gl_lds16(gv + (size_t)s_ * 16384, (dst_) + s_ * 512);           \
  } while (0)

  f32x16 zt0 = (f32x16)0.0f, zt1 = (f32x16)0.0f;  // z^T: d rows, q = lq
  float m = -1e30f, l = 0.f;

  // prologue: each wave stages its half of buffer 0
  if (qg == 0) STAGEK(0, pairbase);
  else         STAGEV(0, pairbase + 4096);
  __syncthreads();  // implicit vmcnt(0): buf0 (both halves) landed

  int cur = 0;
  for (int it = 0; it < 8; ++it) {
    u16* Kw = pairbase + cur * 8192;
    u16* Vw = Kw + 4096;
    short8 ka[2][4];
#pragma unroll
    for (int kg = 0; kg < 2; ++kg)
#pragma unroll
      for (int kc = 0; kc < 4; ++kc)
        ka[kg][kc] = *(const short8*)&Kw[swo(kg * 32 + lq, kc * 2 + hi)];
    short8 va[2][4];
#pragma unroll
    for (int dt = 0; dt < 2; ++dt)
#pragma unroll
      for (int cc = 0; cc < 4; ++cc)
        va[dt][cc] = *(const short8*)&Vw[swo(dt * 32 + lq, cc * 2 + hi)];
    asm volatile("s_waitcnt lgkmcnt(0)" ::: "memory");  // frags in regs
    if (it < 7) {  // stage next tile into alt buffer; lands during compute
      u16* alt = pairbase + (cur ^ 1) * 8192;
      if (qg == 0) STAGEK(it + 1, alt);
      else         STAGEV(it + 1, alt + 4096);
    }

    // S^T[key][q] = K . Q
    f32x16 st0 = (f32x16)0.0f, st1 = (f32x16)0.0f;
    __builtin_amdgcn_s_setprio(1);
#pragma unroll
    for (int kc = 0; kc < 4; ++kc) {
      st0 = __builtin_amdgcn_mfma_f32_32x32x16_bf16(ka[0][kc], qf[kc], st0, 0, 0, 0);
      st1 = __builtin_amdgcn_mfma_f32_32x32x16_bf16(ka[1][kc], qf[kc], st1, 0, 0, 0);
    }
    __builtin_amdgcn_s_setprio(0);

    // lane-local softmax over 32 scores for q = lq (pair lane^32 has rest)
    float pm8[8];
#pragma unroll
    for (int r = 0; r < 8; ++r)
      pm8[r] = fmaxf(fmaxf(st0[r], st0[r + 8]), fmaxf(st1[r], st1[r + 8]));
    float pmax = fmaxf(fmaxf(fmaxf(pm8[0], pm8[1]), fmaxf(pm8[2], pm8[3])),
                       fmaxf(fmaxf(pm8[4], pm8[5]), fmaxf(pm8[6], pm8[7])));
    pmax = fmaxf(pmax, __shfl_xor(pmax, 32));
    if (!__all(pmax <= m + 8.f)) {  // defer-max (T13)
      float mnew = fmaxf(m, pmax);
      float alpha = __builtin_amdgcn_exp2f(m - mnew);
      m = mnew;
      l *= alpha;
#pragma unroll
      for (int r = 0; r < 16; ++r) {
        zt0[r] *= alpha;
        zt1[r] *= alpha;
      }
    }
    float rsa[4] = {0.f, 0.f, 0.f, 0.f};
#pragma unroll
    for (int r = 0; r < 16; ++r) {
      float p0 = __builtin_amdgcn_exp2f(st0[r] - m);
      float p1 = __builtin_amdgcn_exp2f(st1[r] - m);
      st0[r] = p0;
      st1[r] = p1;
      rsa[r & 3] += p0 + p1;
    }
    float rs = (rsa[0] + rsa[1]) + (rsa[2] + rsa[3]);
    rs += __shfl_xor(rs, 32);
    l += rs;

    // P -> bf16 B-fragments via cvt_pk + permlane32_swap (m214v22 recipe)
    short8 pa[4];
#pragma unroll
    for (int c = 0; c < 2; ++c) {
      {
        u32 u0 = cvtpk_bf16(st0[c * 8 + 0], st0[c * 8 + 1]);
        u32 u1 = cvtpk_bf16(st0[c * 8 + 2], st0[c * 8 + 3]);
        u32 u2 = cvtpk_bf16(st0[c * 8 + 4], st0[c * 8 + 5]);
        u32 u3 = cvtpk_bf16(st0[c * 8 + 6], st0[c * 8 + 7]);
        pl32swap(u0, u2);
        pl32swap(u1, u3);
        u32x4 uu;
        uu[0] = u0; uu[1] = u1; uu[2] = u2; uu[3] = u3;
        pa[c] = __builtin_bit_cast(short8, uu);
      }
      {
        u32 u0 = cvtpk_bf16(st1[c * 8 + 0], st1[c * 8 + 1]);
        u32 u1 = cvtpk_bf16(st1[c * 8 + 2], st1[c * 8 + 3]);
        u32 u2 = cvtpk_bf16(st1[c * 8 + 4], st1[c * 8 + 5]);
        u32 u3 = cvtpk_bf16(st1[c * 8 + 6], st1[c * 8 + 7]);
        pl32swap(u0, u2);
        pl32swap(u1, u3);
        u32x4 uu;
        uu[0] = u0; uu[1] = u1; uu[2] = u2; uu[3] = u3;
        pa[2 + c] = __builtin_bit_cast(short8, uu);
      }
    }

    // PV: z^T[d][q] += V^T[d][key] * P[key][q]
    __builtin_amdgcn_s_setprio(1);
#pragma unroll
    for (int cc = 0; cc < 4; ++cc) {
      zt0 = __builtin_amdgcn_mfma_f32_32x32x16_bf16(va[0][cc], pa[cc], zt0, 0, 0, 0);
      zt1 = __builtin_amdgcn_mfma_f32_32x32x16_bf16(va[1][cc], pa[cc], zt1, 0, 0, 0);
    }
    __builtin_amdgcn_s_setprio(0);

    if (it < 7) {
      __syncthreads();  // implicit vmcnt(0): both halves of alt landed
      cur ^= 1;
    }
  }
#undef STAGEK
#undef STAGEV

  __syncthreads();  // all waves done with staging LDS; re-alias for merge
  float (*zp)[64][68] = (float (*)[64][68])smem;        // 69632 B
  float* mp = (float*)(smem + 69632);                   // [4][64]
  float* lp = (float*)(smem + 70656);                   // [4][64]
  u16* zb = (u16*)(smem + 71680);                       // [64][64]

  {  // write partials: row = qg*32+lq, d = dt*32 + (r&3)+8*(r>>2)+4*hi
    int qrow = qg * 32 + lq;
#pragma unroll
    for (int r = 0; r < 16; ++r) {
      int d = (r & 3) + 8 * (r >> 2) + 4 * hi;
      zp[quarter][qrow][d] = zt0[r];
      zp[quarter][qrow][32 + d] = zt1[r];
    }
    if (hi == 0) {
      mp[quarter * 64 + qrow] = m;
      lp[quarter * 64 + qrow] = l;
    }
  }
  __syncthreads();
  {  // merge 4 key-quarter partials; thread t -> (q = t>>3 in 0..63, 8 d's)
    int q = t >> 3, c8 = t & 7;
    float mv0 = mp[q], mv1 = mp[64 + q], mv2 = mp[128 + q], mv3 = mp[192 + q];
    float M = fmaxf(fmaxf(mv0, mv1), fmaxf(mv2, mv3));
    float aw[4];
    aw[0] = __builtin_amdgcn_exp2f(mv0 - M);
    aw[1] = __builtin_amdgcn_exp2f(mv1 - M);
    aw[2] = __builtin_amdgcn_exp2f(mv2 - M);
    aw[3] = __builtin_amdgcn_exp2f(mv3 - M);
    float L = aw[0] * lp[q] + aw[1] * lp[64 + q] + aw[2] * lp[128 + q] + aw[3] * lp[192 + q];
    float rl = 1.0f / L;
    f32x4 acc0 = (f32x4)0.0f, acc1 = (f32x4)0.0f;
#pragma unroll
    for (int w = 0; w < 4; ++w) {
      f32x4 z0 = *(const f32x4*)&zp[w][q][c8 * 8];
      f32x4 z1 = *(const f32x4*)&zp[w][q][c8 * 8 + 4];
      acc0 = acc0 + z0 * aw[w];
      acc1 = acc1 + z1 * aw[w];
    }
    acc0 = acc0 * rl;
    acc1 = acc1 * rl;
    short8 pk;
#pragma unroll
    for (int j = 0; j < 4; ++j) {
      pk[j] = (short)f2bf(acc0[j]);
      pk[4 + j] = (short)f2bf(acc1[j]);
    }
    *(short8*)&zb[q * 64 + ((c8 ^ (q & 7)) * 8)] = pk;
  }
  __syncthreads();
  // fused output projection: out[64 q][512] = z[64][64] @ WoSum[64][512]
  const int quad = lane >> 4, ml = lane & 15;
  short8 zf[4][2];
#pragma unroll
  for (int sub = 0; sub < 4; ++sub)
#pragma unroll
    for (int kc = 0; kc < 2; ++kc)
      zf[sub][kc] = *(const short8*)&zb[swo(sub * 16 + ml, kc * 4 + quad)];
  const size_t ob = (size_t)(b * 2048 + q0);
#pragma unroll
  for (int nt2 = 0; nt2 < 4; ++nt2) {
    int col0 = wv * 64 + nt2 * 16;
    short8 wb0 = *(const short8*)&WoT[(size_t)(col0 + ml) * 64 + quad * 8];
    short8 wb1 = *(const short8*)&WoT[(size_t)(col0 + ml) * 64 + 32 + quad * 8];
#pragma unroll
    for (int sub = 0; sub < 4; ++sub) {
      f32x4 o = (f32x4)0.0f;
      o = __builtin_amdgcn_mfma_f32_16x16x32_bf16(zf[sub][0], wb0, o, 0, 0, 0);
      o = __builtin_amdgcn_mfma_f32_16x16x32_bf16(zf[sub][1], wb1, o, 0, 0, 0);
#pragma unroll
      for (int r = 0; r < 4; ++r)
        out[(ob + sub * 16 + quad * 4 + r) * 512 + col0 + ml] = o[r];
    }
  }
}

extern "C" void kernel_launch(void* const* d_in, const int* in_sizes, int n_in,
                              void* d_out, int out_size, void* d_ws, size_t ws_size,
                              hipStream_t stream) {
  const float* x = (const float*)d_in[0];
  const float* Wq = (const float*)d_in[1];
  const float* Wk = (const float*)d_in[2];
  const float* Wv = (const float*)d_in[3];
  const float* Wo = (const float*)d_in[4];
  float* out = (float*)d_out;

  u16* wf = (u16*)d_ws;            // [12][8][2][64][8] fragment-contiguous W
  u16* wot = wf + 192 * 512;       // [512][64]
  u16* Q = wot + 512 * 64;         // [16384][64]
  u16* K = Q + 16384 * 64;         // [16384][64]
  u16* V = K + 16384 * 64;         // [8][64][2048] (V^T per batch)

  hipLaunchKernelGGL(prep, dim3(512), dim3(256), 0, stream, Wq, Wk, Wv, Wo, wf, wot);
  hipLaunchKernelGGL(qkv_proj, dim3(512), dim3(256), 0, stream, x, wf, Q, K, V);
  hipLaunchKernelGGL(attn_out, dim3(256), dim3(512), 0, stream, Q, K, V, wot, out);
}